// Round 3
// baseline (5816.591 us; speedup 1.0000x reference)
//
#include <hip/hip_runtime.h>
#include <math.h>

#define CIN   3
#define DD    32
#define HH    128
#define WW    128
#define COUTC 24
#define HP    126
#define WP    126

#define TPX     16           // pixel-groups per cout
#define PPT     4            // pixels per thread (along w')
#define TILE_W  64           // TPX * PPT
#define NTH     384          // COUTC * TPX
#define LDSROW  68           // floats per (ci,kh) row (16B aligned stride)
#define SLICE_F (9 * LDSROW) // 612 floats per slice buffer
#define NSTG    153          // 9 rows x 17 float4 staging threads
#define SMPAD   25           // padded stride for softmax LDS

// One depth slice, branchless: zero slot S0, accumulate kd=0/1/2 into S0/S1/S2,
// min S2 when it is a complete valid output (d>=2). S0=d%3, S1=(d+2)%3, S2=(d+1)%3.
// Double-buffered staging: issue next slice's global load before the barrier,
// ds_write it to the other buffer after compute. One barrier per slice.
template<int S0, int S1, int S2>
__device__ __forceinline__ void do_slice(
    int d, int pw,
    const float* __restrict__ xrow,   // per-thread staging base (d=0 address)
    int stg_active, int stg_ldsoff,
    float4& stg,
    const float (&w_r)[81],
    float (&ring)[PPT][3],
    float (&mn)[PPT],
    float* __restrict__ lds_x)
{
  // issue next-slice global load early (latency hides under this slice's compute)
  if (stg_active && (d + 1) < DD)
    stg = *(const float4*)(xrow + (size_t)(d + 1) * (HH * WW));

  __syncthreads();   // buf[d&1] staged; previous slice's reads complete

  const float* bp = lds_x + (d & 1) * SLICE_F;

  #pragma unroll
  for (int q = 0; q < PPT; ++q) ring[q][S0] = 0.0f;

  #pragma unroll
  for (int ci = 0; ci < 3; ++ci) {
    #pragma unroll
    for (int kh = 0; kh < 3; ++kh) {
      const float* rp = bp + (ci * 3 + kh) * LDSROW + 4 * pw;
      float4 a  = *(const float4*)rp;
      float2 b2 = *(const float2*)(rp + 4);
      float p[6] = {a.x, a.y, a.z, a.w, b2.x, b2.y};
      #pragma unroll
      for (int kw = 0; kw < 3; ++kw) {
        const float wv0 = w_r[(ci * 9 + kh * 3 + kw) * 3 + 0];
        const float wv1 = w_r[(ci * 9 + kh * 3 + kw) * 3 + 1];
        const float wv2 = w_r[(ci * 9 + kh * 3 + kw) * 3 + 2];
        #pragma unroll
        for (int q = 0; q < PPT; ++q) {
          ring[q][S0] = fmaf(p[kw + q], wv0, ring[q][S0]);
          ring[q][S1] = fmaf(p[kw + q], wv1, ring[q][S1]);
          ring[q][S2] = fmaf(p[kw + q], wv2, ring[q][S2]);
        }
      }
    }
  }

  if (d >= 2) {          // S2 holds completed conv[d-2]
    #pragma unroll
    for (int q = 0; q < PPT; ++q)
      mn[q] = fminf(mn[q], ring[q][S2]);
  }

  // write next slice into the other buffer (readers wait for next barrier)
  if (stg_active && (d + 1) < DD)
    *(float4*)(lds_x + ((d + 1) & 1) * SLICE_F + stg_ldsoff) = stg;
}

__global__ __launch_bounds__(NTH, 3)
void conv3d_min_softmax_kernel(const float* __restrict__ x,
                               const float* __restrict__ wgt,
                               const float* __restrict__ bias,
                               float* __restrict__ out)
{
  __shared__ __align__(16) float lds_x[2 * SLICE_F];
  __shared__ float lds_sm[TILE_W][SMPAD];
  __shared__ float lds_mx[TILE_W];
  __shared__ float lds_rs[TILE_W];

  const int t  = threadIdx.x;
  const int c  = t >> 4;             // output channel
  const int pw = t & 15;             // pixel group (4 consecutive w')
  const int w0 = blockIdx.x * TILE_W;
  const int hp = blockIdx.y;
  const int bb = blockIdx.z;

  // ---- staging assignment: threads 0..152 each own one float4 of the slice ----
  const int stg_active = (t < NSTG);
  int stg_ldsoff = 0;
  const float* xrow = x;
  if (stg_active) {
    const int row = t / 17;          // 0..8 = ci*3+kh
    const int j   = t - row * 17;    // 0..16
    const int ci  = row / 3;
    const int kh  = row - ci * 3;
    int col = w0 + 4 * j;
    if (col > WW - 4) col = WW - 4;  // clamp; only feeds invalid pixels
    stg_ldsoff = row * LDSROW + 4 * j;
    xrow = x + (size_t)(bb * CIN + ci) * (DD * HH * WW)
             + (size_t)(hp + kh) * WW + col;
  }

  // ---- weights for channel c, kd-fastest: w_r[(ci*9+kh*3+kw)*3+kd] ----
  float w_r[81];
  {
    const float* wc = wgt + c * (CIN * 27);
    #pragma unroll
    for (int ci = 0; ci < 3; ++ci)
      #pragma unroll
      for (int kd = 0; kd < 3; ++kd)
        #pragma unroll
        for (int kh = 0; kh < 3; ++kh)
          #pragma unroll
          for (int kw = 0; kw < 3; ++kw)
            w_r[(ci * 9 + kh * 3 + kw) * 3 + kd] =
                wc[ci * 27 + kd * 9 + kh * 3 + kw];
  }

  float ring[PPT][3];
  float mn[PPT];
  #pragma unroll
  for (int q = 0; q < PPT; ++q) {
    mn[q] = INFINITY;
    ring[q][0] = ring[q][1] = ring[q][2] = 0.0f;
  }

  // ---- prologue: stage slice 0 into buffer 0 ----
  float4 stg = {0.f, 0.f, 0.f, 0.f};
  if (stg_active) {
    stg = *(const float4*)xrow;
    *(float4*)(lds_x + stg_ldsoff) = stg;
  }

  // ---- stream 32 depth slices, ring slots at compile time (period 3) ----
  for (int d0 = 0; d0 < 30; d0 += 3) {
    do_slice<0, 2, 1>(d0,     pw, xrow, stg_active, stg_ldsoff, stg, w_r, ring, mn, lds_x);
    do_slice<1, 0, 2>(d0 + 1, pw, xrow, stg_active, stg_ldsoff, stg, w_r, ring, mn, lds_x);
    do_slice<2, 1, 0>(d0 + 2, pw, xrow, stg_active, stg_ldsoff, stg, w_r, ring, mn, lds_x);
  }
  do_slice<0, 2, 1>(30, pw, xrow, stg_active, stg_ldsoff, stg, w_r, ring, mn, lds_x);
  do_slice<1, 0, 2>(31, pw, xrow, stg_active, stg_ldsoff, stg, w_r, ring, mn, lds_x);

  // ---- epilogue: bias, softmax over 24 channels ----
  const float bval = bias[c];
  float val[PPT];
  #pragma unroll
  for (int q = 0; q < PPT; ++q) val[q] = mn[q] + bval;

  __syncthreads();
  #pragma unroll
  for (int q = 0; q < PPT; ++q)
    lds_sm[pw * PPT + q][c] = val[q];
  __syncthreads();

  if (t < TILE_W) {
    float mx = -INFINITY;
    #pragma unroll
    for (int cc = 0; cc < COUTC; ++cc) mx = fmaxf(mx, lds_sm[t][cc]);
    float s = 0.0f;
    #pragma unroll
    for (int cc = 0; cc < COUTC; ++cc) s += __expf(lds_sm[t][cc] - mx);
    lds_mx[t] = mx;
    lds_rs[t] = 1.0f / s;
  }
  __syncthreads();

  #pragma unroll
  for (int q = 0; q < PPT; ++q) {
    int wp_ = w0 + pw * PPT + q;
    if (wp_ < WP) {
      int pix = pw * PPT + q;
      float o = __expf(val[q] - lds_mx[pix]) * lds_rs[pix];
      out[(((size_t)bb * COUTC + c) * HP + hp) * WP + wp_] = o;
    }
  }
}

extern "C" void kernel_launch(void* const* d_in, const int* in_sizes, int n_in,
                              void* d_out, int out_size, void* d_ws, size_t ws_size,
                              hipStream_t stream)
{
  const float* x    = (const float*)d_in[0];
  const float* wgt  = (const float*)d_in[1];
  const float* bias = (const float*)d_in[2];
  float* out = (float*)d_out;

  dim3 grid(2, HP, 16);
  dim3 block(NTH);
  hipLaunchKernelGGL(conv3d_min_softmax_kernel, grid, block, 0, stream,
                     x, wgt, bias, out);
}

// Round 4
// 2216.773 us; speedup vs baseline: 2.6239x; 2.6239x over previous
//
#include <hip/hip_runtime.h>
#include <math.h>

#define CIN   3
#define DD    32
#define HH    128
#define WW    128
#define COUTC 24
#define HP    126
#define WP    126
#define PLANE (HH * WW)          // 16384

#define NTH     256              // 4 waves = 4 channels per block
#define LDSROW  68               // dwords per staged row (17 float4)
#define RPC     10               // input rows per cin (8 out rows + 2)
#define SLICE_F (CIN * RPC * LDSROW)   // 2040 floats per slice buffer
#define NSLOT   510              // 30 rows * 17 float4 staging slots

// ---- one tap-pair: output row o, kernel row kh, all kw, all kd ----
template<int SA, int SB, int SC>
__device__ __forceinline__ void tap(int o, int kh, int ci,
    const float (&w)[81], const float (&p)[6], float (&ring)[8][3])
{
  #pragma unroll
  for (int kw = 0; kw < 3; ++kw) {
    const float wv0 = w[ci * 27 + 0 + kh * 3 + kw];   // kd=0 -> SA
    const float wv1 = w[ci * 27 + 9 + kh * 3 + kw];   // kd=1 -> SB
    const float wv2 = w[ci * 27 + 18 + kh * 3 + kw];  // kd=2 -> SC
    #pragma unroll
    for (int cc = 0; cc < 4; ++cc) {
      const float xv = p[kw + cc];
      ring[o * 4 + cc][SA] = fmaf(xv, wv0, ring[o * 4 + cc][SA]);
      ring[o * 4 + cc][SB] = fmaf(xv, wv1, ring[o * 4 + cc][SB]);
      ring[o * 4 + cc][SC] = fmaf(xv, wv2, ring[o * 4 + cc][SC]);
    }
  }
}

// One depth slice. S0=d%3 (fresh acc, kd=0), S1=(d+2)%3 (kd=1 -> conv[d-1]),
// S2=(d+1)%3 (kd=2 -> completes conv[d-2] -> min when d>=2).
// Prefetch next slice to regs before barrier, ds_write to other buffer after.
template<int S0, int S1, int S2>
__device__ __forceinline__ void do_slice(
    int d,
    const float* __restrict__ g0, const float* __restrict__ g1, int act1,
    int lo0, int lo1, float4& st0, float4& st1,
    const float (&w)[81], float (&ring)[8][3], float (&mn)[8],
    int rbase, int g4, float* __restrict__ lds)
{
  if (d + 1 < DD) {
    st0 = *(const float4*)(g0 + (size_t)(d + 1) * PLANE);
    if (act1) st1 = *(const float4*)(g1 + (size_t)(d + 1) * PLANE);
  }
  __syncthreads();                       // buf[d&1] fully staged

  const float* bp = lds + (d & 1) * SLICE_F;

  #pragma unroll
  for (int i = 0; i < 8; ++i) ring[i][S0] = 0.0f;

  #pragma unroll
  for (int ci = 0; ci < CIN; ++ci) {
    #pragma unroll
    for (int j = 0; j < 4; ++j) {        // input row rbase+j; pairs o+kh==j
      const float* rp = bp + (ci * RPC + rbase + j) * LDSROW + g4;
      float4 a  = *(const float4*)rp;
      float2 b2 = *(const float2*)(rp + 4);
      float p[6] = {a.x, a.y, a.z, a.w, b2.x, b2.y};
      if (j == 0) { tap<S0,S1,S2>(0, 0, ci, w, p, ring); }
      if (j == 1) { tap<S0,S1,S2>(0, 1, ci, w, p, ring);
                    tap<S0,S1,S2>(1, 0, ci, w, p, ring); }
      if (j == 2) { tap<S0,S1,S2>(0, 2, ci, w, p, ring);
                    tap<S0,S1,S2>(1, 1, ci, w, p, ring); }
      if (j == 3) { tap<S0,S1,S2>(1, 2, ci, w, p, ring); }
    }
  }

  if (d >= 2) {
    #pragma unroll
    for (int i = 0; i < 8; ++i) mn[i] = fminf(mn[i], ring[i][S2]);
  }

  if (d + 1 < DD) {
    float* wb = lds + ((d + 1) & 1) * SLICE_F;
    *(float4*)(wb + lo0) = st0;
    if (act1) *(float4*)(wb + lo1) = st1;
  }
}

__attribute__((amdgpu_waves_per_eu(2, 2)))
__global__ void __launch_bounds__(NTH)
conv3d_min_kernel(const float* __restrict__ x,
                  const float* __restrict__ wgt,
                  const float* __restrict__ bias,
                  float* __restrict__ out)
{
  __shared__ __align__(16) float lds[2 * SLICE_F];   // 16.3 KB

  const int t    = threadIdx.x;
  const int lane = t & 63;
  const int wid  = t >> 6;                 // wave -> one channel
  const int ch   = blockIdx.y * 4 + wid;   // 6 channel-groups
  const int wt   = blockIdx.x & 1;
  const int ht   = blockIdx.x >> 1;        // 16 h-tiles
  const int bb   = blockIdx.z;
  const int hp0  = ht * 8;
  const int w0   = wt * 64;
  const int rp   = lane >> 4;              // row-pair 0..3
  const int g    = lane & 15;              // col-group (4 cols)
  const int rbase = rp * 2;
  const int g4    = g * 4;

  // ---- channel weights -> VGPRs (layout [ci][kd][kh][kw], kept raw) ----
  float w[81];
  {
    const float* wc = wgt + ch * 81;
    #pragma unroll
    for (int i = 0; i < 81; ++i) w[i] = wc[i];
  }

  // ---- staging: 510 float4 slots (30 rows x 17), 2 per thread ----
  const int s1   = t + 256;
  const int act1 = (s1 < NSLOT);
  const int r0 = t / 17,  j0 = t - r0 * 17;
  const int r1 = s1 / 17, j1 = s1 - r1 * 17;
  const int ci0 = r0 / RPC, rr0 = r0 - ci0 * RPC;
  const int ci1 = r1 / RPC, rr1 = r1 - ci1 * RPC;
  int grow0 = hp0 + rr0; grow0 = grow0 > 127 ? 127 : grow0;
  int grow1 = hp0 + rr1; grow1 = grow1 > 127 ? 127 : grow1;
  int gc0 = w0 + j0 * 4; gc0 = gc0 > 124 ? 124 : gc0;   // keeps 16B align
  int gc1 = w0 + j1 * 4; gc1 = gc1 > 124 ? 124 : gc1;
  const float* g0 = x + (size_t)(bb * CIN + ci0) * DD * PLANE + grow0 * WW + gc0;
  const float* g1 = x + (size_t)(bb * CIN + ci1) * DD * PLANE + grow1 * WW + gc1;
  const int lo0 = r0 * LDSROW + j0 * 4;
  const int lo1 = r1 * LDSROW + j1 * 4;

  float ring[8][3];
  float mn[8];
  #pragma unroll
  for (int i = 0; i < 8; ++i) {
    mn[i] = INFINITY;
    ring[i][0] = ring[i][1] = ring[i][2] = 0.0f;
  }

  // ---- prologue: stage slice 0 into buffer 0 ----
  float4 st0 = *(const float4*)g0;
  float4 st1 = make_float4(0.f, 0.f, 0.f, 0.f);
  if (act1) st1 = *(const float4*)g1;
  *(float4*)(lds + lo0) = st0;
  if (act1) *(float4*)(lds + lo1) = st1;

  // ---- stream 32 slices, ring slots compile-time (period 3) ----
  for (int d0 = 0; d0 < 30; d0 += 3) {
    do_slice<0,2,1>(d0,     g0, g1, act1, lo0, lo1, st0, st1, w, ring, mn, rbase, g4, lds);
    do_slice<1,0,2>(d0 + 1, g0, g1, act1, lo0, lo1, st0, st1, w, ring, mn, rbase, g4, lds);
    do_slice<2,1,0>(d0 + 2, g0, g1, act1, lo0, lo1, st0, st1, w, ring, mn, rbase, g4, lds);
  }
  do_slice<0,2,1>(30, g0, g1, act1, lo0, lo1, st0, st1, w, ring, mn, rbase, g4, lds);
  do_slice<1,0,2>(31, g0, g1, act1, lo0, lo1, st0, st1, w, ring, mn, rbase, g4, lds);

  // ---- epilogue: bias + store logits (softmax is kernel 2) ----
  const float bval = bias[ch];
  #pragma unroll
  for (int o = 0; o < 2; ++o) {
    const int grow = hp0 + rbase + o;
    if (grow < HP) {
      float* orow = out + ((size_t)(bb * COUTC + ch) * HP + grow) * WP;
      #pragma unroll
      for (int cc = 0; cc < 4; ++cc) {
        const int gcol = w0 + g4 + cc;
        if (gcol < WP) orow[gcol] = mn[o * 4 + cc] + bval;
      }
    }
  }
}

// ---- kernel 2: in-place softmax over the 24 channels ----
__global__ void __launch_bounds__(256)
softmax_ch_kernel(float* __restrict__ out)
{
  const int idx = blockIdx.x * 256 + threadIdx.x;
  const int npx = 16 * HP * WP;            // 254016
  if (idx >= npx) return;
  const int b  = idx / (HP * WP);
  const int hw = idx - b * (HP * WP);
  float* p = out + (size_t)b * COUTC * HP * WP + hw;

  float v[COUTC];
  float mx = -INFINITY;
  #pragma unroll
  for (int c = 0; c < COUTC; ++c) {
    v[c] = p[(size_t)c * HP * WP];
    mx = fmaxf(mx, v[c]);
  }
  float s = 0.0f;
  #pragma unroll
  for (int c = 0; c < COUTC; ++c) {
    v[c] = __expf(v[c] - mx);
    s += v[c];
  }
  const float r = 1.0f / s;
  #pragma unroll
  for (int c = 0; c < COUTC; ++c)
    p[(size_t)c * HP * WP] = v[c] * r;
}

extern "C" void kernel_launch(void* const* d_in, const int* in_sizes, int n_in,
                              void* d_out, int out_size, void* d_ws, size_t ws_size,
                              hipStream_t stream)
{
  const float* x    = (const float*)d_in[0];
  const float* wgt  = (const float*)d_in[1];
  const float* bias = (const float*)d_in[2];
  float* out = (float*)d_out;

  dim3 grid1(32, 6, 16);                   // (ht*wt, ch-group, batch)
  hipLaunchKernelGGL(conv3d_min_kernel, grid1, dim3(NTH), 0, stream,
                     x, wgt, bias, out);

  const int npx = 16 * HP * WP;
  dim3 grid2((npx + 255) / 256);
  hipLaunchKernelGGL(softmax_ch_kernel, grid2, dim3(256), 0, stream, out);
}